// Round 7
// baseline (117.288 us; speedup 1.0000x reference)
//
#include <hip/hip_runtime.h>
#include <hip/hip_bf16.h>

// Problem constants (from reference): B=4,S=2048,K=2,C=32,D=128,P=128
#define P_  128
#define C_  32
#define D_  128
#define BS_ 8192          // B*S rows
#define PD_ (P_*D_)       // 16384 floats = 64 KB
#define NT_ 64            // partial tables (= K1 grid); 4 MB total vs R4's 16 MB
#define RPW_ 16           // rows per wave in K1 (128 rows/block, 8 waves)

// Kernel 1: per-block privatized means table in LDS -> plain-store writeout.
// NO global atomics (R5/R6 measured ~2.4ns/atomic device-wide: stores win).
// 512 threads = 8 waves; wave w owns rows rbase + w + 8*j, j=0..15, ALL loads
// prefetched before any shuffle/atomic so the 16 chains overlap (R4's 4-deep
// prefetch collapsed the serial chain; same trick, deeper).
__global__ __launch_bounds__(512) void scatter_partials(
    const int* __restrict__ idx, const float* __restrict__ keys,
    const float* __restrict__ values, float* __restrict__ partials)
{
    __shared__ float lmeans[PD_];
    float4* lm4 = (float4*)lmeans;
    const int tid = threadIdx.x;
    for (int i = tid; i < PD_ / 4; i += 512) lm4[i] = float4{0.f, 0.f, 0.f, 0.f};
    __syncthreads();

    const int lane = tid & 63;
    const int wave = tid >> 6;                    // 0..7
    const int rbase = blockIdx.x * 128 + wave;    // rows: rbase + 8*j

    float kv[RPW_], va[RPW_], vb[RPW_];
    int2  ii[RPW_];
    #pragma unroll
    for (int j = 0; j < RPW_; ++j) {
        const int r = rbase + 8 * j;
        kv[j] = keys[(size_t)r * 64 + lane];      // [K=2,C=32] flat
        ii[j] = ((const int2*)idx)[r];            // both partition ids
        va[j] = values[(size_t)r * D_ + lane];
        vb[j] = values[(size_t)r * D_ + 64 + lane];
    }

    #pragma unroll
    for (int j = 0; j < RPW_; ++j) {
        float s = kv[j];
        s += __shfl_xor(s, 16);   // reduce within each 32-lane half
        s += __shfl_xor(s, 8);
        s += __shfl_xor(s, 4);
        s += __shfl_xor(s, 2);
        s += __shfl_xor(s, 1);
        const float ks0 = __shfl(s, 0)  * (1.f / 32.f);  // mean_c keys[r,0,:]
        const float ks1 = __shfl(s, 32) * (1.f / 32.f);  // mean_c keys[r,1,:]
        // stride-1 across lanes -> 2 lanes/bank, conflict-free
        atomicAdd(&lmeans[ii[j].x * D_ + lane],      ks0 * va[j]);
        atomicAdd(&lmeans[ii[j].x * D_ + 64 + lane], ks0 * vb[j]);
        atomicAdd(&lmeans[ii[j].y * D_ + lane],      ks1 * va[j]);
        atomicAdd(&lmeans[ii[j].y * D_ + 64 + lane], ks1 * vb[j]);
    }
    __syncthreads();

    float4* dst = (float4*)(partials + (size_t)blockIdx.x * PD_);
    for (int i = tid; i < PD_ / 4; i += 512) dst[i] = lm4[i];
}

// Kernel 2: means[e] = sum_t partials[t][e], 4 MB read (L2-resident).
// 256 blocks x 256 thr; block owns 64 elements, 4 wave-groups split the
// 64 tables (16 each), cross-group combine through LDS.
__global__ __launch_bounds__(256) void reduce_partials(
    const float* __restrict__ partials, float* __restrict__ means)
{
    __shared__ float red[4][64];
    const int t  = threadIdx.x;
    const int el = t & 63;
    const int g  = t >> 6;                  // table-group 0..3
    const int e  = blockIdx.x * 64 + el;    // element 0..16383
    float s = 0.f;
    #pragma unroll
    for (int j = 0; j < 16; ++j)
        s += partials[(size_t)(g * 16 + j) * PD_ + e];
    red[g][el] = s;
    __syncthreads();
    if (t < 64)
        means[blockIdx.x * 64 + t] = red[0][t] + red[1][t] + red[2][t] + red[3][t];
}

// Kernel 3: thread-per-float4. gid covers BS_*D_/4 = 262144 float4s.
// 32 consecutive lanes share one row -> means gathers are 512B segments.
__global__ __launch_bounds__(256) void emit_out(
    const int* __restrict__ idx, const float* __restrict__ means,
    const float* __restrict__ queries, float* __restrict__ out)
{
    const int gid = blockIdx.x * 256 + threadIdx.x;   // [0, 262144)
    const int row = gid >> 5;                          // 32 float4 per row
    const int d4  = gid & 31;
    const int2 ii = ((const int2*)idx)[row];
    const float4 q = ((const float4*)queries)[gid];
    const float4* m4 = (const float4*)means;
    const float4 a = m4[ii.x * 32 + d4];
    const float4 b = m4[ii.y * 32 + d4];
    float4 o;
    o.x = (a.x + b.x) * q.x;
    o.y = (a.y + b.y) * q.y;
    o.z = (a.z + b.z) * q.z;
    o.w = (a.w + b.w) * q.w;
    ((float4*)out)[gid] = o;
}

extern "C" void kernel_launch(void* const* d_in, const int* in_sizes, int n_in,
                              void* d_out, int out_size, void* d_ws, size_t ws_size,
                              hipStream_t stream) {
    const int*   idx     = (const int*)d_in[0];    // [B,S,K] int32
    const float* keys    = (const float*)d_in[1];  // [B,S,K,C] fp32
    const float* values  = (const float*)d_in[2];  // [B,S,D]  fp32
    const float* queries = (const float*)d_in[3];  // [B,S,D]  fp32
    float* out      = (float*)d_out;
    float* partials = (float*)d_ws;                // NT_ x 64 KB = 4 MB
    float* means    = partials + (size_t)NT_ * PD_;

    scatter_partials<<<NT_, 512, 0, stream>>>(idx, keys, values, partials);
    reduce_partials<<<PD_ / 64, 256, 0, stream>>>(partials, means);
    emit_out<<<(BS_ * D_ / 4) / 256, 256, 0, stream>>>(idx, means, queries, out);
}

// Round 8
// 87.835 us; speedup vs baseline: 1.3353x; 1.3353x over previous
//
#include <hip/hip_runtime.h>
#include <hip/hip_bf16.h>

// Problem constants (from reference): B=4,S=2048,K=2,C=32,D=128,P=128
// R4-verbatim revert: best measured structure (88.4 us).
// Validated by failed perturbations: R5 global-atomic fold (+10us: ~2.4ns/op
// atomic throughput), R6 sharded atomics (+8us), R7 64-block/16-deep prefetch
// (+29us: compiler caps VGPRs at 52 and sinks the prefetch -> serial chain).
#define P_  128
#define C_  32
#define D_  128
#define BS_ 8192          // B*S rows
#define PD_ (P_*D_)       // 16384 floats = 64 KB
#define NB_ 256           // privatized partial tables (= K1 grid)

// Kernel 1: per-block partial means tables in LDS -> ws (non-atomic writeout).
// 512 threads = 8 waves; each wave owns rows rbase + 8*j, j=0..3, fully
// prefetched (16 outstanding global loads, fits in registers) so the 4
// shuffle->LDS-atomic chains overlap instead of serializing.
// 256 blocks x 64KB LDS -> 2 blocks/CU across all 256 CUs.
__global__ __launch_bounds__(512) void scatter_partials(
    const int* __restrict__ idx, const float* __restrict__ keys,
    const float* __restrict__ values, float* __restrict__ partials)
{
    __shared__ float lmeans[PD_];
    float4* lm4 = (float4*)lmeans;
    const int tid = threadIdx.x;
    for (int i = tid; i < PD_ / 4; i += 512) lm4[i] = float4{0.f, 0.f, 0.f, 0.f};
    __syncthreads();

    const int lane = tid & 63;
    const int wave = tid >> 6;                 // 0..7
    const int rbase = blockIdx.x * 32 + wave;  // rows: rbase + 8*j

    float kv[4], va[4], vb[4];
    int2  ii[4];
    #pragma unroll
    for (int j = 0; j < 4; ++j) {
        const int r = rbase + 8 * j;
        kv[j] = keys[(size_t)r * 64 + lane];          // [K=2,C=32] flat
        ii[j] = ((const int2*)idx)[r];                // both partition ids
        va[j] = values[(size_t)r * D_ + lane];
        vb[j] = values[(size_t)r * D_ + 64 + lane];
    }

    #pragma unroll
    for (int j = 0; j < 4; ++j) {
        float s = kv[j];
        s += __shfl_xor(s, 16);   // reduce within each 32-lane half
        s += __shfl_xor(s, 8);
        s += __shfl_xor(s, 4);
        s += __shfl_xor(s, 2);
        s += __shfl_xor(s, 1);
        const float ks0 = __shfl(s, 0)  * (1.f / 32.f);  // mean_c keys[r,0,:]
        const float ks1 = __shfl(s, 32) * (1.f / 32.f);  // mean_c keys[r,1,:]
        // stride-1 across lanes -> 2 lanes/bank, conflict-free
        atomicAdd(&lmeans[ii[j].x * D_ + lane],      ks0 * va[j]);
        atomicAdd(&lmeans[ii[j].x * D_ + 64 + lane], ks0 * vb[j]);
        atomicAdd(&lmeans[ii[j].y * D_ + lane],      ks1 * va[j]);
        atomicAdd(&lmeans[ii[j].y * D_ + 64 + lane], ks1 * vb[j]);
    }
    __syncthreads();

    float4* dst = (float4*)(partials + (size_t)blockIdx.x * PD_);
    for (int i = tid; i < PD_ / 4; i += 512) dst[i] = lm4[i];
}

// Kernel 2: means[e] = sum_b partials[b][e]. 256 blocks x 256 threads;
// block owns 64 elements, the 4 waves split the b-range (64 tables each),
// cross-wave combine through LDS. Every CU gets a block.
__global__ __launch_bounds__(256) void reduce_partials(
    const float* __restrict__ partials, float* __restrict__ means)
{
    __shared__ float red[4][64];
    const int t  = threadIdx.x;
    const int el = t & 63;                  // element within block's chunk
    const int g  = t >> 6;                  // b-group 0..3
    const int e  = blockIdx.x * 64 + el;    // global element 0..16383
    float s = 0.f;
    #pragma unroll 8
    for (int j = 0; j < 64; ++j)
        s += partials[(size_t)(g * 64 + j) * PD_ + e];
    red[g][el] = s;
    __syncthreads();
    if (t < 64)
        means[blockIdx.x * 64 + t] = red[0][t] + red[1][t] + red[2][t] + red[3][t];
}

// Kernel 3: thread-per-float4. gid covers BS_*D_/4 = 262144 float4s.
// 32 consecutive lanes share one row -> means gathers are 512B segments.
__global__ __launch_bounds__(256) void emit_out(
    const int* __restrict__ idx, const float* __restrict__ means,
    const float* __restrict__ queries, float* __restrict__ out)
{
    const int gid = blockIdx.x * 256 + threadIdx.x;   // [0, 262144)
    const int row = gid >> 5;                          // 32 float4 per row
    const int d4  = gid & 31;
    const int2 ii = ((const int2*)idx)[row];
    const float4 q = ((const float4*)queries)[gid];
    const float4* m4 = (const float4*)means;
    const float4 a = m4[ii.x * 32 + d4];
    const float4 b = m4[ii.y * 32 + d4];
    float4 o;
    o.x = (a.x + b.x) * q.x;
    o.y = (a.y + b.y) * q.y;
    o.z = (a.z + b.z) * q.z;
    o.w = (a.w + b.w) * q.w;
    ((float4*)out)[gid] = o;
}

extern "C" void kernel_launch(void* const* d_in, const int* in_sizes, int n_in,
                              void* d_out, int out_size, void* d_ws, size_t ws_size,
                              hipStream_t stream) {
    const int*   idx     = (const int*)d_in[0];    // [B,S,K] int32
    const float* keys    = (const float*)d_in[1];  // [B,S,K,C] fp32
    const float* values  = (const float*)d_in[2];  // [B,S,D]  fp32
    const float* queries = (const float*)d_in[3];  // [B,S,D]  fp32
    float* out = (float*)d_out;
    float* ws  = (float*)d_ws;

    // ws layout: [NB_ partial tables of PD_ floats][1 final means table]
    float* partials = ws;
    float* means    = ws + (size_t)NB_ * PD_;

    scatter_partials<<<NB_, 512, 0, stream>>>(idx, keys, values, partials);
    reduce_partials<<<PD_ / 64, 256, 0, stream>>>(partials, means);
    emit_out<<<(BS_ * D_ / 4) / 256, 256, 0, stream>>>(idx, means, queries, out);
}